// Round 1
// baseline (140.225 us; speedup 1.0000x reference)
//
#include <hip/hip_runtime.h>

// BERT-CRF NER: feats = X[B*T,768] @ W^T[768,13] + b, then per-batch Viterbi
// (255 sequential (max,+) steps over 13 states), softmax max-prob, backtrace.
// B=256, T=256, H=768, L=13, START=11, STOP=12.
//
// Outputs (concatenated float32 in d_out):
//   [0..255]        : (1/T) * max(softmax(ld_final))   per batch
//   [256..65791]    : path[b][t] as float               (B*T)

#define NEGV (-10000.0f)

// ---------------------------------------------------------------- kernel 1 --
// One wave computes 4 consecutive rows. Lane l owns k-slice {4l..4l+3, 256+4l..,
// 512+4l..} (12 floats) of each row (coalesced float4 loads). W staged in LDS.
// 13 accumulators per row per lane; butterfly allreduce over 64 lanes; lane<13
// stores the 13 outputs of each row.
__global__ __launch_bounds__(256) void feats_kernel(
    const float* __restrict__ X,     // [65536, 768]
    const float* __restrict__ W,     // [13, 768]
    const float* __restrict__ bias,  // [13]
    float* __restrict__ feats)       // [65536, 13]
{
  __shared__ float Ws[13 * 768];     // 39936 B
  __shared__ float Bs[16];
  const int tid = threadIdx.x;

  {
    const float4* __restrict__ Wv = reinterpret_cast<const float4*>(W);
    float4* Wsv = reinterpret_cast<float4*>(Ws);
    #pragma unroll
    for (int j = 0; j < 10; ++j) {
      int i = tid + j * 256;
      if (i < 13 * 768 / 4) Wsv[i] = Wv[i];
    }
    if (tid < 13) Bs[tid] = bias[tid];
    if (tid >= 13 && tid < 16) Bs[tid] = 0.0f;
  }
  __syncthreads();

  const int wave = tid >> 6;
  const int lane = tid & 63;
  const long rowBase = (long)blockIdx.x * 16 + wave * 4;

  // Load x slices: 12 coalesced float4 loads per lane (3 per row).
  float x[4][12];
  #pragma unroll
  for (int r = 0; r < 4; ++r) {
    const float* xr = X + (rowBase + r) * 768 + 4 * lane;
    #pragma unroll
    for (int j = 0; j < 3; ++j) {
      float4 v = *reinterpret_cast<const float4*>(xr + 256 * j);
      x[r][4 * j + 0] = v.x; x[r][4 * j + 1] = v.y;
      x[r][4 * j + 2] = v.z; x[r][4 * j + 3] = v.w;
    }
  }

  float acc[4][13];
  #pragma unroll
  for (int r = 0; r < 4; ++r)
    #pragma unroll
    for (int c = 0; c < 13; ++c) acc[r][c] = 0.0f;

  // col loop MUST be fully unrolled: acc indexed by col (keep in registers).
  #pragma unroll
  for (int col = 0; col < 13; ++col) {
    float w[12];
    const float* wp = Ws + col * 768 + 4 * lane;
    #pragma unroll
    for (int j = 0; j < 3; ++j) {
      float4 v = *reinterpret_cast<const float4*>(wp + 256 * j);
      w[4 * j + 0] = v.x; w[4 * j + 1] = v.y;
      w[4 * j + 2] = v.z; w[4 * j + 3] = v.w;
    }
    #pragma unroll
    for (int r = 0; r < 4; ++r)
      #pragma unroll
      for (int k = 0; k < 12; ++k)
        acc[r][col] = fmaf(x[r][k], w[k], acc[r][col]);
  }

  // Butterfly allreduce (sum over 64 lanes) for each of the 52 accumulators.
  #pragma unroll
  for (int r = 0; r < 4; ++r)
    #pragma unroll
    for (int c = 0; c < 13; ++c) {
      float v = acc[r][c];
      v += __shfl_xor(v, 1);
      v += __shfl_xor(v, 2);
      v += __shfl_xor(v, 4);
      v += __shfl_xor(v, 8);
      v += __shfl_xor(v, 16);
      v += __shfl_xor(v, 32);
      acc[r][c] = v;
    }

  // Lane c writes output column c of each row (select with static indices).
  #pragma unroll
  for (int r = 0; r < 4; ++r) {
    float v = acc[r][0];
    #pragma unroll
    for (int c = 1; c < 13; ++c)
      v = (lane == c) ? acc[r][c] : v;
    v += Bs[lane & 15];
    if (lane < 13)
      feats[(rowBase + r) * 13 + lane] = v;
  }
}

// ---------------------------------------------------------------- kernel 2 --
// One wave per batch. Lane 'to' (0..12) keeps trans[to][f] in 13 registers and
// its running ld[to]. Per step: broadcast all 13 ld via v_readlane, 13 adds,
// fmax tree (-> v_max3, critical path depth ~3), argmax off-chain with
// first-index tie semantics. psi nibbles to LDS; backtrace on lane 0 from LDS.
__global__ __launch_bounds__(64) void viterbi_kernel(
    const float* __restrict__ feats,  // [B*T, 13]
    const float* __restrict__ trans,  // [13, 13]
    float* __restrict__ out)          // [256 + 65536] floats
{
  __shared__ float fs[3392];             // feats for this batch: 256*13 used
  __shared__ unsigned char psi[256 * 16];
  __shared__ unsigned char path[256];
  __shared__ float ldf[16];

  const int b = blockIdx.x;
  const int lane = threadIdx.x;

  {  // stage this batch's feats (13312 B) into LDS, coalesced float4
    const float4* src = reinterpret_cast<const float4*>(feats + (long)b * 3328);
    float4* dst = reinterpret_cast<float4*>(fs);
    for (int i = lane; i < 832; i += 64) dst[i] = src[i];
  }
  __syncthreads();

  float tr[13];
  #pragma unroll
  for (int f = 0; f < 13; ++f)
    tr[f] = (lane < 13) ? trans[lane * 13 + f] : -1.0e30f;

  float ld = (lane == 11) ? 0.0f : NEGV;  // START = 11

  for (int t = 1; t < 256; ++t) {
    float c[13];
    #pragma unroll
    for (int f = 0; f < 13; ++f) {
      float lf = __uint_as_float(
          __builtin_amdgcn_readlane(__float_as_uint(ld), f));
      c[f] = tr[f] + lf;
    }
    // value max: shallow tree (v_max3)
    float m0 = fmaxf(fmaxf(c[0], c[1]), c[2]);
    float m1 = fmaxf(fmaxf(c[3], c[4]), c[5]);
    float m2 = fmaxf(fmaxf(c[6], c[7]), c[8]);
    float m3 = fmaxf(fmaxf(c[9], c[10]), c[11]);
    float m  = fmaxf(fmaxf(fmaxf(m0, m1), fmaxf(m2, m3)), c[12]);

    // argmax, first-index on ties (descending assign), off the critical path
    int idx = 0;
    #pragma unroll
    for (int f = 12; f >= 0; --f)
      idx = (c[f] == m) ? f : idx;

    float ft = fs[t * 13 + (lane & 15)];
    if (lane < 13) psi[t * 16 + lane] = (unsigned char)idx;
    ld = m + ft;
  }

  __syncthreads();
  if (lane < 13) ldf[lane] = ld;
  __syncthreads();

  if (lane == 0) {
    float m = ldf[0]; int last = 0;
    #pragma unroll
    for (int i = 1; i < 13; ++i) {
      if (ldf[i] > m) { m = ldf[i]; last = i; }  // strict > keeps first index
    }
    float s = 0.0f;
    #pragma unroll
    for (int i = 0; i < 13; ++i) s += expf(ldf[i] - m);
    // max(softmax) = 1/s ; output0 = max_p / T
    out[b] = 1.0f / (256.0f * s);

    int cur = last;
    path[255] = (unsigned char)last;
    for (int t = 255; t >= 1; --t) {
      cur = psi[t * 16 + cur];
      path[t - 1] = (unsigned char)cur;
    }
  }
  __syncthreads();

  float* po = out + 256 + (long)b * 256;
  #pragma unroll
  for (int j = 0; j < 4; ++j)
    po[lane + 64 * j] = (float)path[lane + 64 * j];
}

// ------------------------------------------------------------------ launch --
extern "C" void kernel_launch(void* const* d_in, const int* in_sizes, int n_in,
                              void* d_out, int out_size, void* d_ws, size_t ws_size,
                              hipStream_t stream) {
  const float* X     = (const float*)d_in[0];  // bert_seq_out [256,256,768]
  const float* W     = (const float*)d_in[1];  // [13,768]
  const float* bias  = (const float*)d_in[2];  // [13]
  const float* trans = (const float*)d_in[3];  // [13,13]
  float* out   = (float*)d_out;
  float* feats = (float*)d_ws;                 // 65536*13 floats = 3.4 MB

  feats_kernel<<<4096, 256, 0, stream>>>(X, W, bias, feats);
  viterbi_kernel<<<256, 64, 0, stream>>>(feats, trans, out);
}